// Round 1
// baseline (3089.623 us; speedup 1.0000x reference)
//
#include <hip/hip_runtime.h>
#include <math.h>

// ---------------- output layout (floats) ----------------
// (rpn_params, rpn_score, rois, roi_index, anchor)
#define OUT_PARAMS 0L
#define OUT_SCORE  1179648L            // 8*36864*4
#define OUT_ROIS   1769472L            // + 8*36864*2
#define OUT_IDX    1779072L            // + 2400*4
#define OUT_ANCH   1781472L            // + 2400

// ---------------- workspace layout (float offsets) ----------------
#define WS_WT     0L                   // 512*9*512 transposed conv weights [c][t][oc]
#define WS_WT2    2359296L             // 512*54    combined 1x1 weights [c][o]
#define WS_MID    2386944L             // 8*512*4096 conv output
#define WS_FG     19164160L            // 8*36864 fg scores
#define WS_KEYS   19459072L            // 8*36864 u32 sort keys
#define WS_BOXES  19753984L            // 8*36864*4 clipped boxes
#define WS_SELKEY 20933632L            // 8*2048 u32
#define WS_SBOX   20950016L            // 8*2048*4 selected boxes
#define WS_SUPP   21081088L            // 8*2000*32 u64 suppression bitmatrix
// total ≈ 88.4 MB

// =============== K1: weight transposes ===============
__global__ void k_transpose_w(const float* __restrict__ conv_w,
                              const float* __restrict__ score_w,
                              const float* __restrict__ params_w,
                              float* __restrict__ Wt, float* __restrict__ wt2) {
  int e = blockIdx.x * 256 + threadIdx.x;
  if (e < 512 * 9 * 512) {
    int oc = e & 511, ct = e >> 9;           // ct = c*9 + t
    Wt[e] = conv_w[oc * 4608 + ct];
  }
  if (e < 512 * 54) {
    int o = e % 54, c = e / 54;
    wt2[e] = (o < 18) ? score_w[o * 512 + c] : params_w[(o - 18) * 512 + c];
  }
}

// =============== K2: 3x3 conv + bias + relu (fp32 vector) ===============
// block tile: 64 oc x (16x16 px); thread micro: 4 oc x 16 px (one row)
__global__ __launch_bounds__(256) void k_conv3x3(
    const float* __restrict__ x, const float* __restrict__ Wt,
    const float* __restrict__ bias, float* __restrict__ mid) {
  __shared__ float sx[8][18][20];   // [c][row][col], cols 0..17 valid, stride 20 for b128 align
  __shared__ float sw[8][9][64];    // [c][tap][oc]

  const int n   = blockIdx.z;
  const int oc0 = blockIdx.y * 64;
  const int r0  = (blockIdx.x >> 2) * 16;
  const int c0  = (blockIdx.x & 3) * 16;
  const int tid = threadIdx.x;
  const int ti  = tid & 15;   // oc group (x4)
  const int tj  = tid >> 4;   // output row 0..15

  float acc0[16], acc1[16], acc2[16], acc3[16];
#pragma unroll
  for (int p = 0; p < 16; ++p) { acc0[p] = 0.f; acc1[p] = 0.f; acc2[p] = 0.f; acc3[p] = 0.f; }

  const float* xn = x + (size_t)n * 512 * 4096;

  for (int ct = 0; ct < 64; ++ct) {
    __syncthreads();
    // stage input patch: 8c x 18rows x 20cols (cols>=18 zero)
    for (int e = tid; e < 2880; e += 256) {
      int c = e / 360, rem = e % 360;
      int row = rem / 20, col = rem % 20;
      int gy = r0 - 1 + row, gx = c0 - 1 + col;
      float v = 0.f;
      if (col < 18 && (unsigned)gy < 64u && (unsigned)gx < 64u)
        v = xn[(ct * 8 + c) * 4096 + gy * 64 + gx];
      sx[c][row][col] = v;
    }
    // stage weights: 8c x 9t x 64oc (coalesced from transposed Wt)
    for (int e = tid; e < 4608; e += 256) {
      int c = e / 576, rem = e % 576;
      int t = rem >> 6, o = rem & 63;
      sw[c][t][o] = Wt[((size_t)(ct * 8 + c) * 9 + t) * 512 + oc0 + o];
    }
    __syncthreads();

    for (int c = 0; c < 8; ++c) {
#pragma unroll
      for (int ky = 0; ky < 3; ++ky) {
        float br[20];
        const float* rowp = &sx[c][tj + ky][0];
        *(float4*)&br[0]  = *(const float4*)&rowp[0];
        *(float4*)&br[4]  = *(const float4*)&rowp[4];
        *(float4*)&br[8]  = *(const float4*)&rowp[8];
        *(float4*)&br[12] = *(const float4*)&rowp[12];
        *(float4*)&br[16] = *(const float4*)&rowp[16];
        const float4 a0 = *(const float4*)&sw[c][ky * 3 + 0][ti * 4];
        const float4 a1 = *(const float4*)&sw[c][ky * 3 + 1][ti * 4];
        const float4 a2 = *(const float4*)&sw[c][ky * 3 + 2][ti * 4];
#pragma unroll
        for (int kx = 0; kx < 3; ++kx) {
          const float4 a = (kx == 0) ? a0 : (kx == 1) ? a1 : a2;
#pragma unroll
          for (int p = 0; p < 16; ++p) {
            const float b = br[kx + p];
            acc0[p] = fmaf(a.x, b, acc0[p]);
            acc1[p] = fmaf(a.y, b, acc1[p]);
            acc2[p] = fmaf(a.z, b, acc2[p]);
            acc3[p] = fmaf(a.w, b, acc3[p]);
          }
        }
      }
    }
  }

  const int gy = r0 + tj;
#define STORE_OC(K, ACC)                                                        \
  {                                                                             \
    int oc = oc0 + ti * 4 + K;                                                  \
    float bv = bias[oc];                                                        \
    float* mp = mid + (((size_t)n * 512 + oc) * 64 + gy) * 64 + c0;             \
    _Pragma("unroll") for (int pg = 0; pg < 4; ++pg) {                          \
      float4 v;                                                                 \
      v.x = fmaxf(ACC[pg * 4 + 0] + bv, 0.f);                                   \
      v.y = fmaxf(ACC[pg * 4 + 1] + bv, 0.f);                                   \
      v.z = fmaxf(ACC[pg * 4 + 2] + bv, 0.f);                                   \
      v.w = fmaxf(ACC[pg * 4 + 3] + bv, 0.f);                                   \
      *(float4*)&mp[pg * 4] = v;                                                \
    }                                                                           \
  }
  STORE_OC(0, acc0) STORE_OC(1, acc1) STORE_OC(2, acc2) STORE_OC(3, acc3)
#undef STORE_OC
}

// =============== K3: 1x1 convs (score 18 + params 36) + softmax ===============
__global__ __launch_bounds__(256) void k_1x1(
    const float* __restrict__ mid, const float* __restrict__ wt2,
    const float* __restrict__ score_b, const float* __restrict__ params_b,
    float* __restrict__ out, float* __restrict__ fg) {
  const int p = blockIdx.x * 256 + threadIdx.x;     // 0..32767
  const int n = p >> 12, hw = p & 4095;
  float acc[54];
#pragma unroll
  for (int o = 0; o < 54; ++o) acc[o] = 0.f;
  const float* m = mid + (size_t)n * 512 * 4096 + hw;
  for (int c = 0; c < 512; ++c) {
    const float mv = m[(size_t)c * 4096];
    const float* w = wt2 + c * 54;   // uniform -> scalar loads
#pragma unroll
    for (int o = 0; o < 54; ++o) acc[o] = fmaf(w[o], mv, acc[o]);
  }
#pragma unroll
  for (int o = 0; o < 18; ++o) acc[o] += score_b[o];
#pragma unroll
  for (int o = 0; o < 36; ++o) acc[18 + o] += params_b[o];

  float* so = out + OUT_SCORE + (size_t)n * 73728 + (size_t)hw * 18;
#pragma unroll
  for (int o = 0; o < 18; ++o) so[o] = acc[o];
  float* po = out + OUT_PARAMS + (size_t)n * 147456 + (size_t)hw * 36;
#pragma unroll
  for (int o = 0; o < 36; ++o) po[o] = acc[18 + o];
  float* f = fg + (size_t)n * 36864 + hw * 9;
#pragma unroll
  for (int a = 0; a < 9; ++a) {
    float d = acc[a * 2 + 1] - acc[a * 2 + 0];
    f[a] = 1.f / (1.f + expf(-d));   // == softmax(...)[1]
  }
}

// =============== K4: anchors, loc2bbox, clip, min-size mask, sort keys ===============
__global__ void k_proposals(const float* __restrict__ out_params,
                            const float* __restrict__ fg,
                            const int* __restrict__ ih_p, const int* __restrict__ iw_p,
                            float* __restrict__ boxes, unsigned int* __restrict__ keys,
                            float* __restrict__ anchor_out) {
  const int g = blockIdx.x * 256 + threadIdx.x;
  if (g >= 8 * 36864) return;
  const int n = g / 36864, i = g % 36864;
  const int hw = i / 9, a = i % 9;
  const float ih = (float)ih_p[0], iw = (float)iw_p[0];
  const float ratios[3] = {0.5f, 1.f, 2.f};
  const float scales[3] = {8.f, 16.f, 32.f};
  const float rr = ratios[a / 3], sc = scales[a % 3];
  const float hs = (16.f * sc) * sqrtf(rr);
  const float ws_ = (16.f * sc) * sqrtf(1.f / rr);
  const float sy = (float)((hw >> 6) * 16);
  const float sx = (float)((hw & 63) * 16);
  // replicate reference arithmetic
  const float ay1 = sy + (8.f - hs * 0.5f),  ax1 = sx + (8.f - ws_ * 0.5f);
  const float ay2 = sy + (8.f + hs * 0.5f),  ax2 = sx + (8.f + ws_ * 0.5f);
  if (n == 0) {
    float4 av; av.x = ay1; av.y = ax1; av.z = ay2; av.w = ax2;
    *(float4*)&anchor_out[(size_t)i * 4] = av;
  }
  const float ah = ay2 - ay1, aw = ax2 - ax1;
  const float acy = ay1 + 0.5f * ah, acx = ax1 + 0.5f * aw;
  const float* loc = out_params + (size_t)n * 147456 + (size_t)i * 4;
  const float dy = loc[0], dx = loc[1], dh = loc[2], dw = loc[3];
  const float cy = dy * ah + acy, cx = dx * aw + acx;
  const float h = expf(dh) * ah, w = expf(dw) * aw;
  const float y1 = fminf(fmaxf(cy - 0.5f * h, 0.f), ih);
  const float x1 = fminf(fmaxf(cx - 0.5f * w, 0.f), iw);
  const float y2 = fminf(fmaxf(cy + 0.5f * h, 0.f), ih);
  const float x2 = fminf(fmaxf(cx + 0.5f * w, 0.f), iw);
  float4 bx; bx.x = y1; bx.y = x1; bx.z = y2; bx.w = x2;
  *(float4*)&boxes[(size_t)g * 4] = bx;
  float s = fg[g];
  if (!((y2 - y1) >= 16.f && (x2 - x1) >= 16.f)) s = -INFINITY;
  const unsigned int b = __float_as_uint(s);
  keys[g] = (b & 0x80000000u) ? ~b : (b | 0x80000000u);
}

// =============== K5: per-image radix-select top-2000 value + bitonic sort ===============
__global__ __launch_bounds__(256) void k_select(
    const unsigned int* __restrict__ keys, const float* __restrict__ boxes,
    unsigned int* __restrict__ selkey, float* __restrict__ sboxes) {
  __shared__ unsigned int hist[4][256];
  __shared__ unsigned long long sel[4096];
  __shared__ unsigned int s_prefix, s_remk, s_cnt;
  const int n = blockIdx.x, tid = threadIdx.x;
  const unsigned int* kk = keys + (size_t)n * 36864;
  if (tid == 0) { s_prefix = 0; s_remk = 2000; s_cnt = 0; }
  const int hslot = tid >> 6;

  for (int byte = 3; byte >= 0; --byte) {
    for (int b2 = tid; b2 < 1024; b2 += 256) ((unsigned int*)hist)[b2] = 0;
    __syncthreads();
    const unsigned pfx = s_prefix;
    const unsigned hmask = (byte == 3) ? 0u : (0xFFFFFFFFu << ((byte + 1) * 8));
    for (int i2 = tid; i2 < 36864; i2 += 256) {
      const unsigned k = kk[i2];
      if ((k & hmask) == (pfx & hmask))
        atomicAdd(&hist[hslot][(k >> (byte * 8)) & 255], 1u);
    }
    __syncthreads();
    if (tid == 0) {
      unsigned rem = s_remk;
      int b2 = 255;
      for (;; --b2) {
        const unsigned c2 = hist[0][b2] + hist[1][b2] + hist[2][b2] + hist[3][b2];
        if (c2 >= rem) break;
        rem -= c2;
      }
      s_prefix = pfx | ((unsigned)b2 << (byte * 8));
      s_remk = rem;
    }
    __syncthreads();
  }
  const unsigned T = s_prefix;

  // compact all keys >= T (count >= 2000 guaranteed)
  for (int i2 = tid; i2 < 36864; i2 += 256) {
    const unsigned k = kk[i2];
    if (k >= T) {
      const unsigned p2 = atomicAdd(&s_cnt, 1u);
      if (p2 < 4096)
        sel[p2] = ((unsigned long long)k << 32) | (unsigned)(~i2);
    }
  }
  __syncthreads();
  unsigned cnt = s_cnt; if (cnt > 4096) cnt = 4096;
  for (int i2 = (int)cnt + tid; i2 < 4096; i2 += 256) sel[i2] = 0ull;

  // bitonic sort, descending by (key, ~idx)  -> top_k tie-break: lower idx first
  for (int k2 = 2; k2 <= 4096; k2 <<= 1) {
    for (int j = k2 >> 1; j > 0; j >>= 1) {
      __syncthreads();
      for (int t = tid; t < 2048; t += 256) {
        const int i1 = (t << 1) - (t & (j - 1));
        const int i2 = i1 + j;
        const unsigned long long va = sel[i1], vb = sel[i2];
        const bool sw = ((i1 & k2) == 0) ? (va < vb) : (va > vb);
        if (sw) { sel[i1] = vb; sel[i2] = va; }
      }
    }
  }
  __syncthreads();

  for (int s2 = tid; s2 < 2048; s2 += 256) {
    const unsigned long long comp = sel[s2];
    unsigned key = (unsigned)(comp >> 32);
    unsigned idx = ~(unsigned)(comp & 0xFFFFFFFFu);
    float4 bx; bx.x = 0.f; bx.y = 0.f; bx.z = 0.f; bx.w = 0.f;
    if (comp != 0ull) bx = *(const float4*)&boxes[((size_t)n * 36864 + idx) * 4];
    else key = 0;
    selkey[n * 2048 + s2] = key;
    *(float4*)&sboxes[((size_t)n * 2048 + s2) * 4] = bx;
  }
}

// =============== K6: NMS suppression bit-matrix ===============
__global__ void k_nms_matrix(const float* __restrict__ sboxes,
                             unsigned long long* __restrict__ supp) {
  const int t = blockIdx.x * 256 + threadIdx.x;
  if (t >= 8 * 2000 * 32) return;
  const int n = t / 64000, rem = t % 64000;
  const int i = rem >> 5, w = rem & 31;
  const float4 bi = *(const float4*)&sboxes[((size_t)n * 2048 + i) * 4];
  const float areai = (bi.z - bi.x) * (bi.w - bi.y);
  unsigned long long bits = 0ull;
  const int j0 = w * 64;
  for (int jj = 0; jj < 64; ++jj) {
    const int j = j0 + jj;
    if (j >= 2000) break;
    const float4 bj = *(const float4*)&sboxes[((size_t)n * 2048 + j) * 4];
    const float areaj = (bj.z - bj.x) * (bj.w - bj.y);
    const float yy1 = fmaxf(bi.x, bj.x), xx1 = fmaxf(bi.y, bj.y);
    const float yy2 = fminf(bi.z, bj.z), xx2 = fminf(bi.w, bj.w);
    const float ih2 = fmaxf(yy2 - yy1, 0.f), iw2 = fmaxf(xx2 - xx1, 0.f);
    const float inter = ih2 * iw2;
    const float iou = inter / (areai + areaj - inter + 1e-9f);
    if (iou > 0.7f) bits |= (1ull << jj);
  }
  supp[((size_t)n * 2000 + i) * 32 + w] = bits;
}

// =============== K7: serial greedy scan (1 wave/image) + write rois ===============
__global__ void k_nms_scan(const unsigned long long* __restrict__ supp,
                           const unsigned int* __restrict__ selkey,
                           const float* __restrict__ sboxes,
                           float* __restrict__ out) {
  const int n = blockIdx.x;
  const int lane = threadIdx.x;   // 64 threads = 1 wave
  const unsigned long long* sp = supp + (size_t)n * 2000 * 32;
  unsigned long long removed = 0ull, keepmask = 0ull;
  unsigned long long rowv = (lane < 32) ? sp[lane] : 0ull;
  for (int i = 0; i < 2000; ++i) {
    const unsigned long long nextv =
        (lane < 32 && i + 1 < 2000) ? sp[(size_t)(i + 1) * 32 + lane] : 0ull;
    const unsigned long long remw = __shfl(removed, i >> 6);
    const bool keep = ((remw >> (i & 63)) & 1ull) == 0ull;
    if (keep) {
      if (lane < 32) removed |= rowv;
      if (lane == (i >> 6)) keepmask |= (1ull << (i & 63));
    }
    rowv = nextv;
  }
  int running = 0;
  for (int ci = 0; ci < 32; ++ci) {
    const unsigned long long km = __shfl(keepmask, ci);
    const int i = ci * 64 + lane;
    const unsigned key = selkey[n * 2048 + i];
    const bool fin = (key >= 0x80000000u);   // isfinite (scores are sigmoid > 0)
    const bool kf = (((km >> lane) & 1ull) != 0ull) && fin;
    const unsigned long long ball = __ballot(kf);
    const int rank = running + __popcll(ball & ((1ull << lane) - 1ull));
    if (kf && rank < 300) {
      const float4 bx = *(const float4*)&sboxes[((size_t)n * 2048 + i) * 4];
      *(float4*)&out[OUT_ROIS + ((size_t)n * 300 + rank) * 4] = bx;
    }
    running += __popcll(ball);
  }
  const int kept = running < 300 ? running : 300;
  for (int r2 = kept + lane; r2 < 300; r2 += 64) {
    float4 z; z.x = 0.f; z.y = 0.f; z.z = 0.f; z.w = 0.f;
    *(float4*)&out[OUT_ROIS + ((size_t)n * 300 + r2) * 4] = z;
  }
  for (int r2 = lane; r2 < 300; r2 += 64)
    out[OUT_IDX + n * 300 + r2] = (float)n;
}

// =============== host ===============
extern "C" void kernel_launch(void* const* d_in, const int* in_sizes, int n_in,
                              void* d_out, int out_size, void* d_ws, size_t ws_size,
                              hipStream_t stream) {
  const float* x        = (const float*)d_in[0];
  const float* conv_w   = (const float*)d_in[1];
  const float* conv_b   = (const float*)d_in[2];
  const float* score_w  = (const float*)d_in[3];
  const float* score_b  = (const float*)d_in[4];
  const float* params_w = (const float*)d_in[5];
  const float* params_b = (const float*)d_in[6];
  const int*   ih       = (const int*)d_in[7];
  const int*   iw       = (const int*)d_in[8];
  float* out = (float*)d_out;
  float* ws  = (float*)d_ws;

  float* Wt      = ws + WS_WT;
  float* wt2     = ws + WS_WT2;
  float* mid     = ws + WS_MID;
  float* fg      = ws + WS_FG;
  unsigned int* keys = (unsigned int*)(ws + WS_KEYS);
  float* boxes   = ws + WS_BOXES;
  unsigned int* selkey = (unsigned int*)(ws + WS_SELKEY);
  float* sboxes  = ws + WS_SBOX;
  unsigned long long* supp = (unsigned long long*)(ws + WS_SUPP);

  hipLaunchKernelGGL(k_transpose_w, dim3(9216), dim3(256), 0, stream,
                     conv_w, score_w, params_w, Wt, wt2);
  hipLaunchKernelGGL(k_conv3x3, dim3(16, 8, 8), dim3(256), 0, stream,
                     x, Wt, conv_b, mid);
  hipLaunchKernelGGL(k_1x1, dim3(128), dim3(256), 0, stream,
                     mid, wt2, score_b, params_b, out, fg);
  hipLaunchKernelGGL(k_proposals, dim3(1152), dim3(256), 0, stream,
                     out + OUT_PARAMS, fg, ih, iw, boxes, keys, out + OUT_ANCH);
  hipLaunchKernelGGL(k_select, dim3(8), dim3(256), 0, stream,
                     keys, boxes, selkey, sboxes);
  hipLaunchKernelGGL(k_nms_matrix, dim3(2000), dim3(256), 0, stream,
                     sboxes, supp);
  hipLaunchKernelGGL(k_nms_scan, dim3(8), dim3(64), 0, stream,
                     supp, selkey, sboxes, out);
}

// Round 3
// 1487.131 us; speedup vs baseline: 2.0776x; 2.0776x over previous
//
#include <hip/hip_runtime.h>
#include <math.h>

typedef _Float16 f16x8 __attribute__((ext_vector_type(8)));
typedef float f32x4 __attribute__((ext_vector_type(4)));
typedef unsigned long long u64;

// ---------------- output layout (floats) ----------------
#define OUT_PARAMS 0L
#define OUT_SCORE  1179648L
#define OUT_ROIS   1769472L
#define OUT_IDX    1779072L
#define OUT_ANCH   1781472L

// ---------------- workspace layout (float offsets) ----------------
#define WS_WT2   0L          // 512*54 f32 (1x1 weights, [c][o])
#define WS_W2H   27648L      // 9*512*512 f16 hi  [tap][oc][c]  (x1024 scaled)
#define WS_W2L   1207296L    // 9*512*512 f16 lo
#define WS_XT    2386944L    // 8*4096*512 f32 NHWC transposed input
#define WS_MID   19164160L   // 8*512*4096 f32 conv output (NCHW)
#define WS_FG    35941376L   // 8*36864 f32
#define WS_KEYS  36236288L   // 8*36864 u32
#define WS_BOX   36531200L   // 8*36864*4 f32
#define WS_SELK  37710848L   // 8*2048 u32
#define WS_SBOX  37727232L   // 8*2048*4 f32
#define WS_SUPP  37792768L   // 8*2000*32 u64
// total = 38,816,768 f32 = 155.3 MB

// =============== K1: weight transform (split f16 hi/lo, x1024) ===============
__global__ void k_transpose_w(const float* __restrict__ conv_w,
                              const float* __restrict__ score_w,
                              const float* __restrict__ params_w,
                              _Float16* __restrict__ W2h, _Float16* __restrict__ W2l,
                              float* __restrict__ wt2) {
  int e = blockIdx.x * 256 + threadIdx.x;
  if (e < 9 * 512 * 512) {
    int tap = e >> 18, rem = e & 262143;
    int oc = rem >> 9, c = rem & 511;
    float v = conv_w[(oc * 512 + c) * 9 + tap] * 1024.0f;
    _Float16 h = (_Float16)v;
    W2h[e] = h;
    W2l[e] = (_Float16)(v - (float)h);
  }
  if (e < 512 * 54) {
    int o = e % 54, c = e / 54;
    wt2[e] = (o < 18) ? score_w[o * 512 + c] : params_w[(o - 18) * 512 + c];
  }
}

// =============== K2: x NCHW f32 -> NHWC f32 transpose ===============
__global__ __launch_bounds__(256) void k_split_x(const float* __restrict__ x,
                                                 float* __restrict__ Xt) {
  __shared__ float t[64][66];
  const int pxb = blockIdx.x;   // image row
  const int c0  = blockIdx.y * 64;
  const int n   = blockIdx.z;
  const int tid = threadIdx.x;
  const int a = tid >> 6, b = tid & 63;
#pragma unroll
  for (int i = 0; i < 16; ++i) {
    int c_l = i * 4 + a;
    t[c_l][b] = x[((size_t)(n * 512 + c0 + c_l) * 4096) + pxb * 64 + b];
  }
  __syncthreads();
#pragma unroll
  for (int i = 0; i < 16; ++i) {
    int px_l = i * 4 + a;
    Xt[((size_t)(n * 4096 + pxb * 64 + px_l) * 512) + c0 + b] = t[b][px_l];
  }
}

// =============== K3: 3x3 conv via f16x3 split MFMA (split accumulators) ===============
// block: 128 oc x 128 px (2 rows x 64 cols), 4 waves, wave tile 64x64
__global__ __launch_bounds__(256, 2) void k_conv_mfma(
    const float* __restrict__ Xt, const _Float16* __restrict__ W2h,
    const _Float16* __restrict__ W2l, const float* __restrict__ bias,
    float* __restrict__ mid) {
  __shared__ _Float16 XH[8448];   // [264 px][32 c], 16B-slot swizzled
  __shared__ _Float16 XL[8448];

  const int n   = blockIdx.x >> 5;
  const int rp  = blockIdx.x & 31;       // row pair
  const int oc0 = blockIdx.y * 128;
  const int tid = threadIdx.x;
  const int lane = tid & 63, wid = tid >> 6;
  const int wm = wid >> 1, wn = wid & 1;
  const int l15 = lane & 15, kg = lane >> 4;

  f32x4 acch[4][4], accl[4][4];
#pragma unroll
  for (int i = 0; i < 4; ++i)
#pragma unroll
    for (int j = 0; j < 4; ++j) {
      acch[i][j] = (f32x4){0.f, 0.f, 0.f, 0.f};
      accl[i][j] = (f32x4){0.f, 0.f, 0.f, 0.f};
    }

  for (int cb = 0; cb < 16; ++cb) {
    __syncthreads();
    // ---- stage X tile: 4 rows x 66 cols x 32 c, f32 -> (x512) f16 hi/lo ----
    for (int u = tid; u < 1056; u += 256) {
      const int px = u >> 2, sd = u & 3;
      const int cg = sd ^ ((px >> 1) & 3);    // source 8c-group for this slot
      const int hrow = px / 66, hcol = px - hrow * 66;
      const int y = rp * 2 - 1 + hrow, xx = hcol - 1;
      float4 v0 = {0.f, 0.f, 0.f, 0.f}, v1 = {0.f, 0.f, 0.f, 0.f};
      if ((unsigned)y < 64u && (unsigned)xx < 64u) {
        const float* s = Xt + (((size_t)(n * 64 + y) * 64 + xx) * 512 + cb * 32 + cg * 8);
        v0 = *(const float4*)s;
        v1 = *(const float4*)(s + 4);
      }
      f16x8 hv, lv;
      float f[8] = {v0.x, v0.y, v0.z, v0.w, v1.x, v1.y, v1.z, v1.w};
#pragma unroll
      for (int e = 0; e < 8; ++e) {
        const float fs = f[e] * 512.0f;        // keep x_lo out of f16 denormals
        _Float16 h = (_Float16)fs;
        hv[e] = h;
        lv[e] = (_Float16)(fs - (float)h);
      }
      *(f16x8*)(XH + u * 8) = hv;
      *(f16x8*)(XL + u * 8) = lv;
    }
    __syncthreads();

    // ---- compute 9 taps ----
#pragma unroll
    for (int ky = 0; ky < 3; ++ky) {
#pragma unroll
      for (int kx = 0; kx < 3; ++kx) {
        const int tap = ky * 3 + kx;
        f16x8 ah[4], al[4], bh[4], bl[4];
#pragma unroll
        for (int mf = 0; mf < 4; ++mf) {
          const size_t aoff =
              ((size_t)(tap * 512 + oc0 + wm * 64 + mf * 16 + l15)) * 512 + cb * 32 + kg * 8;
          ah[mf] = *(const f16x8*)(W2h + aoff);
          al[mf] = *(const f16x8*)(W2l + aoff);
        }
#pragma unroll
        for (int nf = 0; nf < 4; ++nf) {
          const int lpx = (wn + ky) * 66 + nf * 16 + l15 + kx;
          const int off = lpx * 32 + ((kg ^ ((lpx >> 1) & 3)) * 8);
          bh[nf] = *(const f16x8*)(XH + off);
          bl[nf] = *(const f16x8*)(XL + off);
        }
#pragma unroll
        for (int mf = 0; mf < 4; ++mf)
#pragma unroll
          for (int nf = 0; nf < 4; ++nf) {
            acch[mf][nf] = __builtin_amdgcn_mfma_f32_16x16x32_f16(ah[mf], bh[nf], acch[mf][nf], 0, 0, 0);
            accl[mf][nf] = __builtin_amdgcn_mfma_f32_16x16x32_f16(ah[mf], bl[nf], accl[mf][nf], 0, 0, 0);
            accl[mf][nf] = __builtin_amdgcn_mfma_f32_16x16x32_f16(al[mf], bh[nf], accl[mf][nf], 0, 0, 0);
          }
      }
    }
  }

  // ---- epilogue: combine, unscale, bias, relu, store NCHW ----
  const float inv = 1.0f / (1024.0f * 512.0f);
  const int y = rp * 2 + wn;
#pragma unroll
  for (int mf = 0; mf < 4; ++mf) {
#pragma unroll
    for (int r = 0; r < 4; ++r) {
      const int oc = oc0 + wm * 64 + mf * 16 + kg * 4 + r;
      const float bv = bias[oc];
      float* mp = mid + (((size_t)(n * 512 + oc) * 64 + y) * 64);
#pragma unroll
      for (int nf = 0; nf < 4; ++nf) {
        const int xcol = nf * 16 + l15;
        mp[xcol] = fmaxf((acch[mf][nf][r] + accl[mf][nf][r]) * inv + bv, 0.f);
      }
    }
  }
}

// =============== K4: 1x1 convs + softmax ===============
__global__ __launch_bounds__(256) void k_1x1(
    const float* __restrict__ mid, const float* __restrict__ wt2,
    const float* __restrict__ score_b, const float* __restrict__ params_b,
    float* __restrict__ out, float* __restrict__ fg) {
  const int p = blockIdx.x * 256 + threadIdx.x;
  const int n = p >> 12, hw = p & 4095;
  float acc[54];
#pragma unroll
  for (int o = 0; o < 54; ++o) acc[o] = 0.f;
  const float* m = mid + (size_t)n * 512 * 4096 + hw;
  for (int c = 0; c < 512; ++c) {
    const float mv = m[(size_t)c * 4096];
    const float* w = wt2 + c * 54;
#pragma unroll
    for (int o = 0; o < 54; ++o) acc[o] = fmaf(w[o], mv, acc[o]);
  }
#pragma unroll
  for (int o = 0; o < 18; ++o) acc[o] += score_b[o];
#pragma unroll
  for (int o = 0; o < 36; ++o) acc[18 + o] += params_b[o];

  float* so = out + OUT_SCORE + (size_t)n * 73728 + (size_t)hw * 18;
#pragma unroll
  for (int o = 0; o < 18; ++o) so[o] = acc[o];
  float* po = out + OUT_PARAMS + (size_t)n * 147456 + (size_t)hw * 36;
#pragma unroll
  for (int o = 0; o < 36; ++o) po[o] = acc[18 + o];
  float* f = fg + (size_t)n * 36864 + hw * 9;
#pragma unroll
  for (int a = 0; a < 9; ++a) {
    float d = acc[a * 2 + 1] - acc[a * 2 + 0];
    f[a] = 1.f / (1.f + expf(-d));
  }
}

// =============== K5: anchors, loc2bbox, clip, min-size, sort keys ===============
__global__ void k_proposals(const float* __restrict__ out_params,
                            const float* __restrict__ fg,
                            const int* __restrict__ ih_p, const int* __restrict__ iw_p,
                            float* __restrict__ boxes, unsigned int* __restrict__ keys,
                            float* __restrict__ anchor_out) {
  const int g = blockIdx.x * 256 + threadIdx.x;
  if (g >= 8 * 36864) return;
  const int n = g / 36864, i = g % 36864;
  const int hw = i / 9, a = i % 9;
  const float ih = (float)ih_p[0], iw = (float)iw_p[0];
  const float ratios[3] = {0.5f, 1.f, 2.f};
  const float scales[3] = {8.f, 16.f, 32.f};
  const float rr = ratios[a / 3], sc = scales[a % 3];
  const float hs = (16.f * sc) * sqrtf(rr);
  const float ws_ = (16.f * sc) * sqrtf(1.f / rr);
  const float sy = (float)((hw >> 6) * 16);
  const float sx = (float)((hw & 63) * 16);
  const float ay1 = sy + (8.f - hs * 0.5f), ax1 = sx + (8.f - ws_ * 0.5f);
  const float ay2 = sy + (8.f + hs * 0.5f), ax2 = sx + (8.f + ws_ * 0.5f);
  if (n == 0) {
    float4 av; av.x = ay1; av.y = ax1; av.z = ay2; av.w = ax2;
    *(float4*)&anchor_out[(size_t)i * 4] = av;
  }
  const float ah = ay2 - ay1, aw = ax2 - ax1;
  const float acy = ay1 + 0.5f * ah, acx = ax1 + 0.5f * aw;
  const float* loc = out_params + (size_t)n * 147456 + (size_t)i * 4;
  const float dy = loc[0], dx = loc[1], dh = loc[2], dw = loc[3];
  const float cy = dy * ah + acy, cx = dx * aw + acx;
  const float h = expf(dh) * ah, w = expf(dw) * aw;
  const float y1 = fminf(fmaxf(cy - 0.5f * h, 0.f), ih);
  const float x1 = fminf(fmaxf(cx - 0.5f * w, 0.f), iw);
  const float y2 = fminf(fmaxf(cy + 0.5f * h, 0.f), ih);
  const float x2 = fminf(fmaxf(cx + 0.5f * w, 0.f), iw);
  float4 bx; bx.x = y1; bx.y = x1; bx.z = y2; bx.w = x2;
  *(float4*)&boxes[(size_t)g * 4] = bx;
  float s = fg[g];
  if (!((y2 - y1) >= 16.f && (x2 - x1) >= 16.f)) s = -INFINITY;
  const unsigned int b = __float_as_uint(s);
  keys[g] = (b & 0x80000000u) ? ~b : (b | 0x80000000u);
}

// =============== K6: radix-select top-2000 + bitonic sort ===============
__global__ __launch_bounds__(256) void k_select(
    const unsigned int* __restrict__ keys, const float* __restrict__ boxes,
    unsigned int* __restrict__ selkey, float* __restrict__ sboxes) {
  __shared__ unsigned int hist[4][256];
  __shared__ unsigned long long sel[4096];
  __shared__ unsigned int s_prefix, s_remk, s_cnt;
  const int n = blockIdx.x, tid = threadIdx.x;
  const unsigned int* kk = keys + (size_t)n * 36864;
  if (tid == 0) { s_prefix = 0; s_remk = 2000; s_cnt = 0; }
  const int hslot = tid >> 6;

  for (int byte = 3; byte >= 0; --byte) {
    for (int b2 = tid; b2 < 1024; b2 += 256) ((unsigned int*)hist)[b2] = 0;
    __syncthreads();
    const unsigned pfx = s_prefix;
    const unsigned hmask = (byte == 3) ? 0u : (0xFFFFFFFFu << ((byte + 1) * 8));
    for (int i2 = tid; i2 < 36864; i2 += 256) {
      const unsigned k = kk[i2];
      if ((k & hmask) == (pfx & hmask))
        atomicAdd(&hist[hslot][(k >> (byte * 8)) & 255], 1u);
    }
    __syncthreads();
    if (tid == 0) {
      unsigned rem = s_remk;
      int b2 = 255;
      for (;; --b2) {
        const unsigned c2 = hist[0][b2] + hist[1][b2] + hist[2][b2] + hist[3][b2];
        if (c2 >= rem) break;
        rem -= c2;
      }
      s_prefix = pfx | ((unsigned)b2 << (byte * 8));
      s_remk = rem;
    }
    __syncthreads();
  }
  const unsigned T = s_prefix;

  for (int i2 = tid; i2 < 36864; i2 += 256) {
    const unsigned k = kk[i2];
    if (k >= T) {
      const unsigned p2 = atomicAdd(&s_cnt, 1u);
      if (p2 < 4096)
        sel[p2] = ((unsigned long long)k << 32) | (unsigned)(~i2);
    }
  }
  __syncthreads();
  unsigned cnt = s_cnt; if (cnt > 4096) cnt = 4096;
  for (int i2 = (int)cnt + tid; i2 < 4096; i2 += 256) sel[i2] = 0ull;

  for (int k2 = 2; k2 <= 4096; k2 <<= 1) {
    for (int j = k2 >> 1; j > 0; j >>= 1) {
      __syncthreads();
      for (int t = tid; t < 2048; t += 256) {
        const int i1 = (t << 1) - (t & (j - 1));
        const int i2 = i1 + j;
        const unsigned long long va = sel[i1], vb = sel[i2];
        const bool sw = ((i1 & k2) == 0) ? (va < vb) : (va > vb);
        if (sw) { sel[i1] = vb; sel[i2] = va; }
      }
    }
  }
  __syncthreads();

  for (int s2 = tid; s2 < 2048; s2 += 256) {
    const unsigned long long comp = sel[s2];
    unsigned key = (unsigned)(comp >> 32);
    unsigned idx = ~(unsigned)(comp & 0xFFFFFFFFu);
    float4 bx; bx.x = 0.f; bx.y = 0.f; bx.z = 0.f; bx.w = 0.f;
    if (comp != 0ull) bx = *(const float4*)&boxes[((size_t)n * 36864 + idx) * 4];
    else key = 0;
    selkey[n * 2048 + s2] = key;
    *(float4*)&sboxes[((size_t)n * 2048 + s2) * 4] = bx;
  }
}

// =============== K7: NMS suppression bit-matrix ===============
__global__ void k_nms_matrix(const float* __restrict__ sboxes,
                             unsigned long long* __restrict__ supp) {
  const int t = blockIdx.x * 256 + threadIdx.x;
  if (t >= 8 * 2000 * 32) return;
  const int n = t / 64000, rem = t % 64000;
  const int i = rem >> 5, w = rem & 31;
  const float4 bi = *(const float4*)&sboxes[((size_t)n * 2048 + i) * 4];
  const float areai = (bi.z - bi.x) * (bi.w - bi.y);
  unsigned long long bits = 0ull;
  const int j0 = w * 64;
  for (int jj = 0; jj < 64; ++jj) {
    const int j = j0 + jj;
    if (j >= 2000) break;
    const float4 bj = *(const float4*)&sboxes[((size_t)n * 2048 + j) * 4];
    const float areaj = (bj.z - bj.x) * (bj.w - bj.y);
    const float yy1 = fmaxf(bi.x, bj.x), xx1 = fmaxf(bi.y, bj.y);
    const float yy2 = fminf(bi.z, bj.z), xx2 = fminf(bi.w, bj.w);
    const float ih2 = fmaxf(yy2 - yy1, 0.f), iw2 = fmaxf(xx2 - xx1, 0.f);
    const float inter = ih2 * iw2;
    const float iou = inter / (areai + areaj - inter + 1e-9f);
    if (iou > 0.7f) bits |= (1ull << jj);
  }
  supp[((size_t)n * 2000 + i) * 32 + w] = bits;
}

// =============== K8: serial greedy scan, 8-deep prefetch ===============
__global__ void k_nms_scan(const unsigned long long* __restrict__ supp,
                           const unsigned int* __restrict__ selkey,
                           const float* __restrict__ sboxes,
                           float* __restrict__ out) {
  const int n = blockIdx.x;
  const int lane = threadIdx.x;   // 64 threads = 1 wave
  const unsigned long long* sp = supp + (size_t)n * 64000;
  const bool ld = lane < 32;
  unsigned long long removed = 0ull, keepmask = 0ull;
#define LDROW(i) (ld ? sp[(size_t)(i) * 32 + lane] : 0ull)
  unsigned long long r0 = LDROW(0), r1 = LDROW(1), r2 = LDROW(2), r3 = LDROW(3),
                     r4 = LDROW(4), r5 = LDROW(5), r6 = LDROW(6), r7 = LDROW(7);
  for (int g = 0; g < 250; ++g) {
    unsigned long long n0 = 0, n1 = 0, n2 = 0, n3 = 0, n4 = 0, n5 = 0, n6 = 0, n7 = 0;
    if (g < 249) {
      const int nb = (g + 1) * 8;
      n0 = LDROW(nb); n1 = LDROW(nb + 1); n2 = LDROW(nb + 2); n3 = LDROW(nb + 3);
      n4 = LDROW(nb + 4); n5 = LDROW(nb + 5); n6 = LDROW(nb + 6); n7 = LDROW(nb + 7);
    }
#define STEP(K, RK)                                                       \
    {                                                                     \
      const int i = g * 8 + K;                                            \
      const unsigned long long remw = __shfl(removed, i >> 6);            \
      if (!((remw >> (i & 63)) & 1ull)) {                                 \
        if (ld) removed |= RK;                                            \
        if (lane == (i >> 6)) keepmask |= (1ull << (i & 63));             \
      }                                                                   \
    }
    STEP(0, r0) STEP(1, r1) STEP(2, r2) STEP(3, r3)
    STEP(4, r4) STEP(5, r5) STEP(6, r6) STEP(7, r7)
#undef STEP
    r0 = n0; r1 = n1; r2 = n2; r3 = n3; r4 = n4; r5 = n5; r6 = n6; r7 = n7;
  }
#undef LDROW
  int running = 0;
  for (int ci = 0; ci < 32; ++ci) {
    const unsigned long long km = __shfl(keepmask, ci);
    const int i = ci * 64 + lane;
    const unsigned key = selkey[n * 2048 + i];
    const bool fin = (key >= 0x80000000u);
    const bool kf = (((km >> lane) & 1ull) != 0ull) && fin;
    const unsigned long long ball = __ballot(kf);
    const int rank = running + __popcll(ball & ((1ull << lane) - 1ull));
    if (kf && rank < 300) {
      const float4 bx = *(const float4*)&sboxes[((size_t)n * 2048 + i) * 4];
      *(float4*)&out[OUT_ROIS + ((size_t)n * 300 + rank) * 4] = bx;
    }
    running += __popcll(ball);
  }
  const int kept = running < 300 ? running : 300;
  for (int r2 = kept + lane; r2 < 300; r2 += 64) {
    float4 z; z.x = 0.f; z.y = 0.f; z.z = 0.f; z.w = 0.f;
    *(float4*)&out[OUT_ROIS + ((size_t)n * 300 + r2) * 4] = z;
  }
  for (int r2 = lane; r2 < 300; r2 += 64)
    out[OUT_IDX + n * 300 + r2] = (float)n;
}

// =============== host ===============
extern "C" void kernel_launch(void* const* d_in, const int* in_sizes, int n_in,
                              void* d_out, int out_size, void* d_ws, size_t ws_size,
                              hipStream_t stream) {
  const float* x        = (const float*)d_in[0];
  const float* conv_w   = (const float*)d_in[1];
  const float* conv_b   = (const float*)d_in[2];
  const float* score_w  = (const float*)d_in[3];
  const float* score_b  = (const float*)d_in[4];
  const float* params_w = (const float*)d_in[5];
  const float* params_b = (const float*)d_in[6];
  const int*   ih       = (const int*)d_in[7];
  const int*   iw       = (const int*)d_in[8];
  float* out = (float*)d_out;
  float* ws  = (float*)d_ws;

  float* wt2 = ws + WS_WT2;
  _Float16* W2h = (_Float16*)(ws + WS_W2H);
  _Float16* W2l = (_Float16*)(ws + WS_W2L);
  float* Xt  = ws + WS_XT;
  float* mid = ws + WS_MID;
  float* fg  = ws + WS_FG;
  unsigned int* keys = (unsigned int*)(ws + WS_KEYS);
  float* boxes = ws + WS_BOX;
  unsigned int* selkey = (unsigned int*)(ws + WS_SELK);
  float* sboxes = ws + WS_SBOX;
  u64* supp = (u64*)(ws + WS_SUPP);

  hipLaunchKernelGGL(k_transpose_w, dim3(9216), dim3(256), 0, stream,
                     conv_w, score_w, params_w, W2h, W2l, wt2);
  hipLaunchKernelGGL(k_split_x, dim3(64, 8, 8), dim3(256), 0, stream, x, Xt);
  hipLaunchKernelGGL(k_conv_mfma, dim3(256, 4), dim3(256), 0, stream,
                     Xt, W2h, W2l, conv_b, mid);
  hipLaunchKernelGGL(k_1x1, dim3(128), dim3(256), 0, stream,
                     mid, wt2, score_b, params_b, out, fg);
  hipLaunchKernelGGL(k_proposals, dim3(1152), dim3(256), 0, stream,
                     out + OUT_PARAMS, fg, ih, iw, boxes, keys, out + OUT_ANCH);
  hipLaunchKernelGGL(k_select, dim3(8), dim3(256), 0, stream,
                     keys, boxes, selkey, sboxes);
  hipLaunchKernelGGL(k_nms_matrix, dim3(2000), dim3(256), 0, stream,
                     sboxes, supp);
  hipLaunchKernelGGL(k_nms_scan, dim3(8), dim3(64), 0, stream,
                     supp, selkey, sboxes, out);
}